// Round 11
// baseline (715.690 us; speedup 1.0000x reference)
//
#include <hip/hip_runtime.h>
#include <math.h>

#define B_   2
#define S_   3072
#define C_   256
#define NH   8
#define HD   32
#define HALF 16
#define NELEM (B_*S_*C_)   // 1,572,864
#define MLROWS (B_*NH*S_)  // 49,152 rows per split
#define TABN  (S_*HALF)    // 49,152 rope table entries

__device__ __forceinline__ float dot4(float4 a, float4 b) {
    return a.x*b.x + a.y*b.y + a.z*b.z + a.w*b.w;
}

// direct global->LDS copy, 16B per lane; LDS dest is wave-uniform base + lane*16
__device__ __forceinline__ void gload_lds16(const float* g, float* l) {
    __builtin_amdgcn_global_load_lds(
        (const __attribute__((address_space(1))) unsigned int*)g,
        (__attribute__((address_space(3))) unsigned int*)l, 16, 0, 0);
}

// ---------------- GEMM: out[M x 256] = (A[M x 256] @ W[256 x 256]^T (+bias))*scl ---
__device__ __forceinline__ void gemm_nt_body(const float* __restrict__ A,
                                             const float* __restrict__ W,
                                             const float* __restrict__ bias,
                                             float* __restrict__ out,
                                             float scl)
{
    __shared__ float As[64][36];
    __shared__ float Ws[64][36];
    const int tid  = threadIdx.x;
    const int tx4  = (tid & 15) * 4;
    const int ty4  = (tid >> 4) * 4;
    const int row0 = blockIdx.x * 64;
    const int col0 = blockIdx.y * 64;

    float acc[4][4] = {};

    for (int kc = 0; kc < C_; kc += 32) {
        __syncthreads();
        #pragma unroll
        for (int l = tid; l < 512; l += 256) {
            const int r  = l >> 3;
            const int k4 = (l & 7) * 4;
            *(float4*)&As[r][k4] = *(const float4*)&A[(size_t)(row0 + r)*C_ + kc + k4];
            *(float4*)&Ws[r][k4] = *(const float4*)&W[(size_t)(col0 + r)*C_ + kc + k4];
        }
        __syncthreads();
        #pragma unroll
        for (int k4 = 0; k4 < 32; k4 += 4) {
            float4 a0 = *(const float4*)&As[ty4+0][k4];
            float4 a1 = *(const float4*)&As[ty4+1][k4];
            float4 a2 = *(const float4*)&As[ty4+2][k4];
            float4 a3 = *(const float4*)&As[ty4+3][k4];
            float4 w0 = *(const float4*)&Ws[tx4+0][k4];
            float4 w1 = *(const float4*)&Ws[tx4+1][k4];
            float4 w2 = *(const float4*)&Ws[tx4+2][k4];
            float4 w3 = *(const float4*)&Ws[tx4+3][k4];
            acc[0][0] += dot4(a0,w0); acc[0][1] += dot4(a0,w1);
            acc[0][2] += dot4(a0,w2); acc[0][3] += dot4(a0,w3);
            acc[1][0] += dot4(a1,w0); acc[1][1] += dot4(a1,w1);
            acc[1][2] += dot4(a1,w2); acc[1][3] += dot4(a1,w3);
            acc[2][0] += dot4(a2,w0); acc[2][1] += dot4(a2,w1);
            acc[2][2] += dot4(a2,w2); acc[2][3] += dot4(a2,w3);
            acc[3][0] += dot4(a3,w0); acc[3][1] += dot4(a3,w1);
            acc[3][2] += dot4(a3,w2); acc[3][3] += dot4(a3,w3);
        }
    }

    float4 bv = make_float4(0.f, 0.f, 0.f, 0.f);
    if (bias) bv = *(const float4*)&bias[col0 + tx4];
    #pragma unroll
    for (int rr = 0; rr < 4; ++rr) {
        float4 o = make_float4((acc[rr][0] + bv.x)*scl, (acc[rr][1] + bv.y)*scl,
                               (acc[rr][2] + bv.z)*scl, (acc[rr][3] + bv.w)*scl);
        *(float4*)&out[(size_t)(row0 + ty4 + rr)*C_ + col0 + tx4] = o;
    }
}

__global__ __launch_bounds__(256) void qkv_kernel(
        const float* __restrict__ x,
        const float* __restrict__ Wq, const float* __restrict__ Wk, const float* __restrict__ Wv,
        const float* __restrict__ qb, const float* __restrict__ vb,
        float* __restrict__ q, float* __restrict__ k, float* __restrict__ v)
{
    // scale 1/sqrt(32) folded into q projection (RoPE rotation commutes with scalar)
    if      (blockIdx.z == 0) gemm_nt_body(x, Wq, qb,      q, 0.17677669529663687f);
    else if (blockIdx.z == 1) gemm_nt_body(x, Wk, nullptr, k, 1.0f);
    else                      gemm_nt_body(x, Wv, vb,      v, 1.0f);
}

__global__ __launch_bounds__(256) void out_gemm_kernel(
        const float* __restrict__ ctx, const float* __restrict__ Wo,
        const float* __restrict__ bo, float* __restrict__ out)
{
    gemm_nt_body(ctx, Wo, bo, out, 1.0f);
}

// ---------------- RoPE table: the 49152 unique (s,j) angle pairs ------------------
// Same double-precision math as the inline version -> bit-identical rope.
__global__ __launch_bounds__(256) void rope_tab_kernel(float2* __restrict__ tbl)
{
    const int idx = blockIdx.x * 256 + threadIdx.x;   // 0..49151
    const int j = idx & 15;
    const int s = idx >> 4;
    const double invf = exp(-log(10000.0) * (double)j * (1.0 / 16.0));
    const float  angf = (float)((double)s * invf);
    double sn, cs;
    sincos((double)angf, &sn, &cs);
    tbl[idx] = make_float2((float)cs, (float)sn);
}

// ---------------- RoPE (in place on q and k) --------------------------------------
template<bool TAB>
__global__ __launch_bounds__(256) void rope_kernel(float* __restrict__ q, float* __restrict__ k,
                                                   const float2* __restrict__ tbl)
{
    const int idx = blockIdx.x * 256 + threadIdx.x;
    const int per_tensor = B_ * S_ * NH * HALF;       // 786432
    float* t = (idx < per_tensor) ? q : k;
    const int i   = (idx < per_tensor) ? idx : idx - per_tensor;
    const int j   = i & 15;
    const int hh  = (i >> 4) & 7;
    const int row = i >> 7;
    const int s   = (row >= S_) ? (row - S_) : row;

    float c, sf;
    if (TAB) {
        const float2 cs2 = tbl[(s << 4) | j];
        c = cs2.x; sf = cs2.y;
    } else {
        const double invf = exp(-log(10000.0) * (double)j * (1.0 / 16.0));
        const float  angf = (float)((double)s * invf);
        double sn, cd;
        sincos((double)angf, &sn, &cd);
        c = (float)cd; sf = (float)sn;
    }

    const size_t base = (size_t)row * C_ + hh * HD + j;
    const float t1 = t[base];
    const float t2 = t[base + HALF];
    t[base]        = t1 * c - t2 * sf;
    t[base + HALF] = t2 * c + t1 * sf;
}

// ---------------- attn per-tile compute (KVBLK=16, r=2, defer-max) ----------------
// ALL LDS reads are base-VGPR + compile-time immediate: lK/lV = lbase + const,
// lbase = &SM + sub*32 (the row term), column loop runs over PHYSICAL index p.
// Q registers are pre-permuted (slot p holds logical group p^sub), so products
// pair correctly with zero per-tile address or index VALU. acc is in the same
// permuted slot space (consistent per lane); unpermuted once in the epilogue.
__device__ __forceinline__ void attn_tile(const float* __restrict__ lK,
                                          const float* __restrict__ lV,
                                          const float* __restrict__ q0,
                                          const float* __restrict__ q1,
                                          float& m0, float& m1,
                                          float& l0, float& l1,
                                          float* __restrict__ a0,
                                          float* __restrict__ a1)
{
    __builtin_amdgcn_s_setprio(1);
    // ---- scores: 4 cols x 2 rows; each K float4 read feeds 8 FMAs
    float s0_[4], s1_[4];
    #pragma unroll
    for (int i = 0; i < 4; ++i) {
        float d0 = 0.f, d1 = 0.f;
        #pragma unroll
        for (int p = 0; p < 8; ++p) {
            float4 kk = *(const float4*)&lK[i*128 + p*4];   // imm offset
            d0 += q0[p*4+0]*kk.x + q0[p*4+1]*kk.y + q0[p*4+2]*kk.z + q0[p*4+3]*kk.w;
            d1 += q1[p*4+0]*kk.x + q1[p*4+1]*kk.y + q1[p*4+2]*kk.z + q1[p*4+3]*kk.w;
        }
        s0_[i] = d0; s1_[i] = d1;
    }

    // ---- online softmax with defer-max (T13, THR=8)
    {
        float tm0 = fmaxf(fmaxf(s0_[0], s0_[1]), fmaxf(s0_[2], s0_[3]));
        float tm1 = fmaxf(fmaxf(s1_[0], s1_[1]), fmaxf(s1_[2], s1_[3]));
        tm0 = fmaxf(tm0, __shfl_xor(tm0, 1)); tm0 = fmaxf(tm0, __shfl_xor(tm0, 2));
        tm1 = fmaxf(tm1, __shfl_xor(tm1, 1)); tm1 = fmaxf(tm1, __shfl_xor(tm1, 2));
        if (!__all((tm0 - m0 <= 8.f) && (tm1 - m1 <= 8.f))) {
            const float mn0 = fmaxf(m0, tm0), mn1 = fmaxf(m1, tm1);
            const float f0 = __expf(m0 - mn0), f1 = __expf(m1 - mn1);
            m0 = mn0; m1 = mn1;
            l0 *= f0; l1 *= f1;
            #pragma unroll
            for (int d = 0; d < 32; ++d) { a0[d] *= f0; a1[d] *= f1; }
        }
        #pragma unroll
        for (int i = 0; i < 4; ++i) {
            s0_[i] = __expf(s0_[i] - m0);     // bounded by e^8 when deferred
            s1_[i] = __expf(s1_[i] - m1);
        }
        l0 += (s0_[0] + s0_[1]) + (s0_[2] + s0_[3]);
        l1 += (s1_[0] + s1_[1]) + (s1_[2] + s1_[3]);
    }

    // ---- PV: each V float4 read feeds 8 FMAs; accumulate in permuted slots
    #pragma unroll
    for (int i = 0; i < 4; ++i) {
        const float p0 = s0_[i], p1 = s1_[i];
        #pragma unroll
        for (int p = 0; p < 8; ++p) {
            float4 vv = *(const float4*)&lV[i*128 + p*4];   // imm offset
            a0[p*4+0] += p0*vv.x; a0[p*4+1] += p0*vv.y;
            a0[p*4+2] += p0*vv.z; a0[p*4+3] += p0*vv.w;
            a1[p*4+0] += p1*vv.x; a1[p*4+1] += p1*vv.y;
            a1[p*4+2] += p1*vv.z; a1[p*4+3] += p1*vv.w;
        }
    }
    __builtin_amdgcn_s_setprio(0);
}

// swap float4-groups A and B of a 32-float register array (compile-time indices)
__device__ __forceinline__ void swap_group(float* a, int A, int B) {
    #pragma unroll
    for (int j = 0; j < 4; ++j) { float t = a[A*4+j]; a[A*4+j] = a[B*4+j]; a[B*4+j] = t; }
}

// ---------------- Flash attention, fp32, split-KV, KVBLK=16, 12 waves/CU ----------
// R9 structure (validated 405us: 1-wave blocks, depth-1 prefetch, 2 buffers,
// defer-max, source-swizzle, VGPR=128 -> all 12 blocks/CU resident) plus:
//  - zero per-tile LDS address VALU (see attn_tile header comment)
//  - x2 unrolled loop so the buffer index is compile-time
// HARD CONSTRAINT (R10 lesson): VGPR must stay <= 128 — the HW occupancy step
// at 128 is worth more than any pipeline depth (R10: 152 VGPR -> 11.7% occ, +30%).
template<int NSPLIT>
__global__ __launch_bounds__(64) void attn_kernel(
        const float* __restrict__ q, const float* __restrict__ k,
        const float* __restrict__ v, float* __restrict__ outp,
        float* __restrict__ pm, float* __restrict__ pl)
{
    __shared__ float SM[2][2][16*32];   // [buf][0=K,1=V][row*32 + phys col]  8 KB

    const int tid  = threadIdx.x;
    const int sub  = tid & 3;
    const int g    = tid >> 2;                 // 0..15
    const int qb   = blockIdx.x * 32;
    const int hh   = blockIdx.y;
    const int split = blockIdx.z % NSPLIT;
    const int b     = blockIdx.z / NSPLIT;
    const int kt0   = split * (S_ / NSPLIT);
    const int NT    = (S_ / NSPLIT) / 16;      // 96 (split-2) or 192; both even

    const size_t rowbase = (size_t)b * S_;
    const int coloff = hh * HD;

    // staging: lane covers tile-rows srow and srow+8; source col pre-swizzled so
    // LDS physical col4 (tid&7) receives logical col4 (tid&7)^(row&3)
    const int srow  = tid >> 3;                          // 0..7
    const int sxcol = (((tid & 7) ^ (srow & 3)) << 2);   // swizzled float col
    const float* kstage = &k[(rowbase + kt0 + srow)*C_ + coloff + sxcol];
    const float* vstage = &v[(rowbase + kt0 + srow)*C_ + coloff + sxcol];

    const int r0 = qb + g, r1 = qb + g + 16;

#define ISSUE_TILE(t_, bufi) { \
        const float* gk = kstage + (size_t)(t_)*(16*C_); \
        const float* gv = vstage + (size_t)(t_)*(16*C_); \
        float* lk = &SM[bufi][0][0]; \
        float* lv = &SM[bufi][1][0]; \
        gload_lds16(gk        , lk      ); \
        gload_lds16(gk +  8*C_, lk + 256); \
        gload_lds16(gv        , lv      ); \
        gload_lds16(gv +  8*C_, lv + 256); }

    // start tile 0 fetch before q-row loads
    ISSUE_TILE(0, 0);

    // q rows -> registers, PERMUTED: slot p holds logical group p^sub
    float q0[32], q1[32];                      // scale already folded into q
    #pragma unroll
    for (int p = 0; p < 8; ++p) {
        const int lg = (p ^ sub) << 2;
        float4 t0 = *(const float4*)&q[(rowbase + r0)*C_ + coloff + lg];
        float4 t1 = *(const float4*)&q[(rowbase + r1)*C_ + coloff + lg];
        q0[p*4+0]=t0.x; q0[p*4+1]=t0.y; q0[p*4+2]=t0.z; q0[p*4+3]=t0.w;
        q1[p*4+0]=t1.x; q1[p*4+1]=t1.y; q1[p*4+2]=t1.z; q1[p*4+3]=t1.w;
    }

    float m0 = -1e30f, m1 = -1e30f;
    float l0 = 0.f, l1 = 0.f;
    float a0[32] = {}, a1[32] = {};

    // single per-lane LDS base: row term sub*32 folded in; buffers/columns are
    // compile-time immediates off this pointer (buf*1024, V +512, i*128, p*4)
    const float* lbase = &SM[0][0][0] + sub*32;

#define TILE_BODY(tt, BUF) { \
        if ((tt) + 1 < NT) { \
            ISSUE_TILE((tt) + 1, (BUF) ^ 1); \
            asm volatile("s_waitcnt vmcnt(4)" ::: "memory"); \
        } else { \
            asm volatile("s_waitcnt vmcnt(0)" ::: "memory"); \
        } \
        __builtin_amdgcn_sched_barrier(0); \
        attn_tile(lbase + (BUF)*1024, lbase + (BUF)*1024 + 512, \
                  q0, q1, m0, m1, l0, l1, a0, a1); }

    for (int t = 0; t < NT; t += 2) {
        TILE_BODY(t,     0);
        TILE_BODY(t + 1, 1);
    }
#undef TILE_BODY
#undef ISSUE_TILE

    // ---- unpermute acc: slot p holds logical group p^sub (involution -> swaps),
    // inside a 4-way sub branch so all indices are compile-time
    if (sub == 1) {
        swap_group(a0,0,1); swap_group(a0,2,3); swap_group(a0,4,5); swap_group(a0,6,7);
        swap_group(a1,0,1); swap_group(a1,2,3); swap_group(a1,4,5); swap_group(a1,6,7);
    } else if (sub == 2) {
        swap_group(a0,0,2); swap_group(a0,1,3); swap_group(a0,4,6); swap_group(a0,5,7);
        swap_group(a1,0,2); swap_group(a1,1,3); swap_group(a1,4,6); swap_group(a1,5,7);
    } else if (sub == 3) {
        swap_group(a0,0,3); swap_group(a0,1,2); swap_group(a0,4,7); swap_group(a0,5,6);
        swap_group(a1,0,3); swap_group(a1,1,2); swap_group(a1,4,7); swap_group(a1,5,6);
    }

    // ---- reduce across the 4-lane group; normalize only if single-pass
    l0 += __shfl_xor(l0, 1); l0 += __shfl_xor(l0, 2);
    l1 += __shfl_xor(l1, 1); l1 += __shfl_xor(l1, 2);
    const float inv0 = (NSPLIT == 1) ? 1.f / l0 : 1.f;
    const float inv1 = (NSPLIT == 1) ? 1.f / l1 : 1.f;
    #pragma unroll
    for (int d = 0; d < 32; ++d) {
        float x0 = a0[d]; x0 += __shfl_xor(x0, 1); x0 += __shfl_xor(x0, 2); a0[d] = x0 * inv0;
        float x1 = a1[d]; x1 += __shfl_xor(x1, 1); x1 += __shfl_xor(x1, 2); a1[d] = x1 * inv1;
    }

    float* obase = (NSPLIT == 1) ? outp : (outp + (size_t)split * NELEM);
    // static-index writes: 4-way branch on sub keeps arrays out of scratch
    #define WRITE_SLICE(ro, a_, off) { \
        float4 o1 = make_float4(a_[(off)+0],a_[(off)+1],a_[(off)+2],a_[(off)+3]); \
        float4 o2 = make_float4(a_[(off)+4],a_[(off)+5],a_[(off)+6],a_[(off)+7]); \
        *(float4*)&obase[(rowbase + (ro))*C_ + coloff + (off)]     = o1; \
        *(float4*)&obase[(rowbase + (ro))*C_ + coloff + (off) + 4] = o2; }
    if      (sub == 0) { WRITE_SLICE(r0, a0, 0)  WRITE_SLICE(r1, a1, 0)  }
    else if (sub == 1) { WRITE_SLICE(r0, a0, 8)  WRITE_SLICE(r1, a1, 8)  }
    else if (sub == 2) { WRITE_SLICE(r0, a0, 16) WRITE_SLICE(r1, a1, 16) }
    else               { WRITE_SLICE(r0, a0, 24) WRITE_SLICE(r1, a1, 24) }
    #undef WRITE_SLICE

    if (NSPLIT > 1 && sub == 0) {
        const size_t mlb = (size_t)split*MLROWS + ((size_t)b*NH + hh)*S_;
        pm[mlb + r0] = m0; pl[mlb + r0] = l0;
        pm[mlb + r1] = m1; pl[mlb + r1] = l1;
    }
}

// ---------------- combine the NSPLIT KV-split partials ---------------------------
template<int NSPLIT>
__global__ __launch_bounds__(256) void combine_kernel(
        const float* __restrict__ pacc, const float* __restrict__ pm,
        const float* __restrict__ pl, float* __restrict__ ctx)
{
    const int gid = blockIdx.x * 256 + threadIdx.x;   // 0 .. B_*S_*NH*8-1
    int rem = gid >> 3;
    const int h = rem & 7; rem >>= 3;
    const int s = rem % S_;
    const int b = rem / S_;

    const size_t i0 = ((size_t)b*NH + h)*S_ + s;
    float mm[NSPLIT], ll[NSPLIT], w[NSPLIT];
    float M = -1e30f;
    #pragma unroll
    for (int i = 0; i < NSPLIT; ++i) {
        mm[i] = pm[i0 + (size_t)i*MLROWS];
        ll[i] = pl[i0 + (size_t)i*MLROWS];
        M = fmaxf(M, mm[i]);
    }
    float L = 0.f;
    #pragma unroll
    for (int i = 0; i < NSPLIT; ++i) { w[i] = __expf(mm[i] - M); L += ll[i]*w[i]; }
    const float invL = 1.f / L;

    const size_t a = (size_t)gid * 4;
    float4 o = make_float4(0.f, 0.f, 0.f, 0.f);
    #pragma unroll
    for (int i = 0; i < NSPLIT; ++i) {
        const float4 x = *(const float4*)&pacc[a + (size_t)i*NELEM];
        o.x += x.x*w[i]; o.y += x.y*w[i]; o.z += x.z*w[i]; o.w += x.w*w[i];
    }
    o.x *= invL; o.y *= invL; o.z *= invL; o.w *= invL;
    *(float4*)&ctx[a] = o;
}

// ---------------- launch ---------------------------------------------------------
extern "C" void kernel_launch(void* const* d_in, const int* in_sizes, int n_in,
                              void* d_out, int out_size, void* d_ws, size_t ws_size,
                              hipStream_t stream)
{
    const float* x  = (const float*)d_in[0];
    const float* Wq = (const float*)d_in[1];
    const float* Wk = (const float*)d_in[2];
    const float* Wv = (const float*)d_in[3];
    const float* qb = (const float*)d_in[4];
    const float* vb = (const float*)d_in[5];
    const float* Wo = (const float*)d_in[6];
    const float* bo = (const float*)d_in[7];
    float* out = (float*)d_out;

    float* ws   = (float*)d_ws;
    float* q    = ws;
    float* k    = q + NELEM;
    float* v    = k + NELEM;
    float* ctx  = v + NELEM;
    float* tblf = ctx + NELEM;                         // rope table: TABN float2
    float* pacc = tblf + 2*TABN;                       // NSPLIT x NELEM

    const size_t need2 = ((size_t)(4+2)*NELEM + (size_t)2*TABN
                          + (size_t)2*2*MLROWS) * sizeof(float);

    // q,k,v projections (+bias, q pre-scaled), 64x64 tiles
    qkv_kernel<<<dim3(96, 4, 3), 256, 0, stream>>>(x, Wq, Wk, Wv, qb, vb, q, k, v);

    if (ws_size >= need2) {
        float2* tbl = (float2*)tblf;
        float* pm = pacc + (size_t)2*NELEM;
        float* pl = pm + (size_t)2*MLROWS;
        // rope via precomputed table (bit-identical double sincos, 32x fewer)
        rope_tab_kernel<<<TABN/256, 256, 0, stream>>>(tbl);
        rope_kernel<true><<<6144, 256, 0, stream>>>(q, k, tbl);
        // 3072 single-wave blocks -> 12 resident/CU -> 3 waves/SIMD
        attn_kernel<2><<<dim3(S_/32, NH, B_*2), 64, 0, stream>>>(q, k, v, pacc, pm, pl);
        combine_kernel<2><<<(B_*S_*NH*8)/256, 256, 0, stream>>>(pacc, pm, pl, ctx);
    } else {
        rope_kernel<false><<<6144, 256, 0, stream>>>(q, k, nullptr);
        attn_kernel<1><<<dim3(S_/32, NH, B_), 64, 0, stream>>>(q, k, v, ctx, nullptr, nullptr);
    }

    // output projection
    out_gemm_kernel<<<dim3(96, 4, 1), 256, 0, stream>>>(ctx, Wo, bo, out);
}

// Round 12
// 492.387 us; speedup vs baseline: 1.4535x; 1.4535x over previous
//
#include <hip/hip_runtime.h>
#include <math.h>

#define B_   2
#define S_   3072
#define C_   256
#define NH   8
#define HD   32
#define HALF 16
#define NELEM (B_*S_*C_)   // 1,572,864
#define MLROWS (B_*NH*S_)  // 49,152 rows per split
#define TABN  (S_*HALF)    // 49,152 rope table entries

__device__ __forceinline__ float dot4(float4 a, float4 b) {
    return a.x*b.x + a.y*b.y + a.z*b.z + a.w*b.w;
}

// direct global->LDS copy, 16B per lane; LDS dest is wave-uniform base + lane*16
__device__ __forceinline__ void gload_lds16(const float* g, float* l) {
    __builtin_amdgcn_global_load_lds(
        (const __attribute__((address_space(1))) unsigned int*)g,
        (__attribute__((address_space(3))) unsigned int*)l, 16, 0, 0);
}

// ---------------- GEMM: out[M x 256] = (A[M x 256] @ W[256 x 256]^T (+bias))*scl ---
__device__ __forceinline__ void gemm_nt_body(const float* __restrict__ A,
                                             const float* __restrict__ W,
                                             const float* __restrict__ bias,
                                             float* __restrict__ out,
                                             float scl)
{
    __shared__ float As[64][36];
    __shared__ float Ws[64][36];
    const int tid  = threadIdx.x;
    const int tx4  = (tid & 15) * 4;
    const int ty4  = (tid >> 4) * 4;
    const int row0 = blockIdx.x * 64;
    const int col0 = blockIdx.y * 64;

    float acc[4][4] = {};

    for (int kc = 0; kc < C_; kc += 32) {
        __syncthreads();
        #pragma unroll
        for (int l = tid; l < 512; l += 256) {
            const int r  = l >> 3;
            const int k4 = (l & 7) * 4;
            *(float4*)&As[r][k4] = *(const float4*)&A[(size_t)(row0 + r)*C_ + kc + k4];
            *(float4*)&Ws[r][k4] = *(const float4*)&W[(size_t)(col0 + r)*C_ + kc + k4];
        }
        __syncthreads();
        #pragma unroll
        for (int k4 = 0; k4 < 32; k4 += 4) {
            float4 a0 = *(const float4*)&As[ty4+0][k4];
            float4 a1 = *(const float4*)&As[ty4+1][k4];
            float4 a2 = *(const float4*)&As[ty4+2][k4];
            float4 a3 = *(const float4*)&As[ty4+3][k4];
            float4 w0 = *(const float4*)&Ws[tx4+0][k4];
            float4 w1 = *(const float4*)&Ws[tx4+1][k4];
            float4 w2 = *(const float4*)&Ws[tx4+2][k4];
            float4 w3 = *(const float4*)&Ws[tx4+3][k4];
            acc[0][0] += dot4(a0,w0); acc[0][1] += dot4(a0,w1);
            acc[0][2] += dot4(a0,w2); acc[0][3] += dot4(a0,w3);
            acc[1][0] += dot4(a1,w0); acc[1][1] += dot4(a1,w1);
            acc[1][2] += dot4(a1,w2); acc[1][3] += dot4(a1,w3);
            acc[2][0] += dot4(a2,w0); acc[2][1] += dot4(a2,w1);
            acc[2][2] += dot4(a2,w2); acc[2][3] += dot4(a2,w3);
            acc[3][0] += dot4(a3,w0); acc[3][1] += dot4(a3,w1);
            acc[3][2] += dot4(a3,w2); acc[3][3] += dot4(a3,w3);
        }
    }

    float4 bv = make_float4(0.f, 0.f, 0.f, 0.f);
    if (bias) bv = *(const float4*)&bias[col0 + tx4];
    #pragma unroll
    for (int rr = 0; rr < 4; ++rr) {
        float4 o = make_float4((acc[rr][0] + bv.x)*scl, (acc[rr][1] + bv.y)*scl,
                               (acc[rr][2] + bv.z)*scl, (acc[rr][3] + bv.w)*scl);
        *(float4*)&out[(size_t)(row0 + ty4 + rr)*C_ + col0 + tx4] = o;
    }
}

__global__ __launch_bounds__(256) void qkv_kernel(
        const float* __restrict__ x,
        const float* __restrict__ Wq, const float* __restrict__ Wk, const float* __restrict__ Wv,
        const float* __restrict__ qb, const float* __restrict__ vb,
        float* __restrict__ q, float* __restrict__ k, float* __restrict__ v)
{
    // scale 1/sqrt(32) folded into q projection (RoPE rotation commutes with scalar)
    if      (blockIdx.z == 0) gemm_nt_body(x, Wq, qb,      q, 0.17677669529663687f);
    else if (blockIdx.z == 1) gemm_nt_body(x, Wk, nullptr, k, 1.0f);
    else                      gemm_nt_body(x, Wv, vb,      v, 1.0f);
}

__global__ __launch_bounds__(256) void out_gemm_kernel(
        const float* __restrict__ ctx, const float* __restrict__ Wo,
        const float* __restrict__ bo, float* __restrict__ out)
{
    gemm_nt_body(ctx, Wo, bo, out, 1.0f);
}

// ---------------- RoPE table: the 49152 unique (s,j) angle pairs ------------------
// Same double-precision math as the inline version -> bit-identical rope.
__global__ __launch_bounds__(256) void rope_tab_kernel(float2* __restrict__ tbl)
{
    const int idx = blockIdx.x * 256 + threadIdx.x;   // 0..49151
    const int j = idx & 15;
    const int s = idx >> 4;
    const double invf = exp(-log(10000.0) * (double)j * (1.0 / 16.0));
    const float  angf = (float)((double)s * invf);
    double sn, cs;
    sincos((double)angf, &sn, &cs);
    tbl[idx] = make_float2((float)cs, (float)sn);
}

// ---------------- RoPE (in place on q and k) --------------------------------------
template<bool TAB>
__global__ __launch_bounds__(256) void rope_kernel(float* __restrict__ q, float* __restrict__ k,
                                                   const float2* __restrict__ tbl)
{
    const int idx = blockIdx.x * 256 + threadIdx.x;
    const int per_tensor = B_ * S_ * NH * HALF;       // 786432
    float* t = (idx < per_tensor) ? q : k;
    const int i   = (idx < per_tensor) ? idx : idx - per_tensor;
    const int j   = i & 15;
    const int hh  = (i >> 4) & 7;
    const int row = i >> 7;
    const int s   = (row >= S_) ? (row - S_) : row;

    float c, sf;
    if (TAB) {
        const float2 cs2 = tbl[(s << 4) | j];
        c = cs2.x; sf = cs2.y;
    } else {
        const double invf = exp(-log(10000.0) * (double)j * (1.0 / 16.0));
        const float  angf = (float)((double)s * invf);
        double sn, cd;
        sincos((double)angf, &sn, &cd);
        c = (float)cd; sf = (float)sn;
    }

    const size_t base = (size_t)row * C_ + hh * HD + j;
    const float t1 = t[base];
    const float t2 = t[base + HALF];
    t[base]        = t1 * c - t2 * sf;
    t[base + HALF] = t2 * c + t1 * sf;
}

// ---------------- Flash attention, fp32, split-KV, KVBLK=16, 12 waves/CU ----------
// EXACT R9 structure (validated 405us attn, VALUBusy 67%, 0 conflicts, VGPR 128):
// 1 wave (64 thr) per block, 32 q-rows: group g = tid>>2 owns rows qb+g+{0,16};
// sub = tid&3 splits the 16 kv-cols 4 ways. No barriers; depth-1 prefetch with
// counted vmcnt. defer-max (T13, THR=8). Source-swizzled LDS.
//
// TWO HARD CONSTRAINTS (R10/R11 lessons — do not touch):
//  - VGPR <= 128 (HW occupancy step: 129+ halves waves/CU; R10: 152 -> +30% time)
//  - the read pattern kr[(c4^sub)<<2] with kr = base + (sub+4*i)*32: the per-lane
//    PHYSICAL column (c4^sub) is what makes reads conflict-free (R11 read uniform
//    physical cols -> 7.5e7 conflicts, the R6 failure re-created).
template<int NSPLIT>
__global__ __launch_bounds__(64) void attn_kernel(
        const float* __restrict__ q, const float* __restrict__ k,
        const float* __restrict__ v, float* __restrict__ outp,
        float* __restrict__ pm, float* __restrict__ pl)
{
    __shared__ float SM[2][2][16*32];   // [buf][0=K,1=V][row*32 + phys col]  8 KB

    const int tid  = threadIdx.x;
    const int sub  = tid & 3;
    const int g    = tid >> 2;                 // 0..15
    const int qb   = blockIdx.x * 32;
    const int hh   = blockIdx.y;
    const int split = blockIdx.z % NSPLIT;
    const int b     = blockIdx.z / NSPLIT;
    const int kt0   = split * (S_ / NSPLIT);
    const int NT    = (S_ / NSPLIT) / 16;      // 96 (split-2) or 192 tiles

    const size_t rowbase = (size_t)b * S_;
    const int coloff = hh * HD;

    // staging: lane covers tile-rows srow and srow+8; source col pre-swizzled so
    // LDS physical col4 (tid&7) receives logical col4 (tid&7)^(row&3);
    // (srow+8)&3 == srow&3 so one formula serves both gloads.
    const int srow  = tid >> 3;                          // 0..7
    const int sxcol = (((tid & 7) ^ (srow & 3)) << 2);   // swizzled float col
    const float* kstage = &k[(rowbase + kt0 + srow)*C_ + coloff + sxcol];
    const float* vstage = &v[(rowbase + kt0 + srow)*C_ + coloff + sxcol];

    const int r0 = qb + g, r1 = qb + g + 16;

#define ISSUE_TILE(t_, bufi) { \
        const float* gk = kstage + (size_t)(t_)*(16*C_); \
        const float* gv = vstage + (size_t)(t_)*(16*C_); \
        float* lk = &SM[bufi][0][0]; \
        float* lv = &SM[bufi][1][0]; \
        gload_lds16(gk        , lk      ); \
        gload_lds16(gk +  8*C_, lk + 256); \
        gload_lds16(gv        , lv      ); \
        gload_lds16(gv +  8*C_, lv + 256); }

    // start tile 0 fetch before q-row loads
    ISSUE_TILE(0, 0);

    float q0[32], q1[32];                      // scale already folded into q
    #pragma unroll
    for (int k4 = 0; k4 < 32; k4 += 4) {
        float4 t0 = *(const float4*)&q[(rowbase + r0)*C_ + coloff + k4];
        float4 t1 = *(const float4*)&q[(rowbase + r1)*C_ + coloff + k4];
        q0[k4+0]=t0.x; q0[k4+1]=t0.y; q0[k4+2]=t0.z; q0[k4+3]=t0.w;
        q1[k4+0]=t1.x; q1[k4+1]=t1.y; q1[k4+2]=t1.z; q1[k4+3]=t1.w;
    }

    float m0 = -1e30f, m1 = -1e30f;
    float l0 = 0.f, l1 = 0.f;
    float a0[32] = {}, a1[32] = {};

    for (int t = 0; t < NT; ++t) {
        const int cur = t & 1;
        if (t + 1 < NT) {
            ISSUE_TILE(t + 1, cur ^ 1);                       // prefetch next tile
            asm volatile("s_waitcnt vmcnt(4)" ::: "memory");  // tile t landed
        } else {
            asm volatile("s_waitcnt vmcnt(0)" ::: "memory");
        }
        __builtin_amdgcn_sched_barrier(0);

        const float* Kc = &SM[cur][0][0];
        const float* Vc = &SM[cur][1][0];

        __builtin_amdgcn_s_setprio(1);
        // ---- scores: 4 cols x 2 rows; each K float4 read feeds 8 FMAs
        float s0_[4], s1_[4];
        #pragma unroll
        for (int i = 0; i < 4; ++i) {
            const float* kr = Kc + (sub + 4*i)*32;
            float d0 = 0.f, d1 = 0.f;
            #pragma unroll
            for (int c4 = 0; c4 < 8; ++c4) {
                float4 kk = *(const float4*)&kr[(c4 ^ sub) << 2];
                d0 += q0[c4*4+0]*kk.x + q0[c4*4+1]*kk.y + q0[c4*4+2]*kk.z + q0[c4*4+3]*kk.w;
                d1 += q1[c4*4+0]*kk.x + q1[c4*4+1]*kk.y + q1[c4*4+2]*kk.z + q1[c4*4+3]*kk.w;
            }
            s0_[i] = d0; s1_[i] = d1;
        }

        // ---- online softmax with defer-max (T13): rescale only when the wave's
        // tile max grew > 8 over the running max (rare after the first tile)
        {
            float tm0 = fmaxf(fmaxf(s0_[0], s0_[1]), fmaxf(s0_[2], s0_[3]));
            float tm1 = fmaxf(fmaxf(s1_[0], s1_[1]), fmaxf(s1_[2], s1_[3]));
            tm0 = fmaxf(tm0, __shfl_xor(tm0, 1)); tm0 = fmaxf(tm0, __shfl_xor(tm0, 2));
            tm1 = fmaxf(tm1, __shfl_xor(tm1, 1)); tm1 = fmaxf(tm1, __shfl_xor(tm1, 2));
            if (!__all((tm0 - m0 <= 8.f) && (tm1 - m1 <= 8.f))) {
                const float mn0 = fmaxf(m0, tm0), mn1 = fmaxf(m1, tm1);
                const float f0 = __expf(m0 - mn0), f1 = __expf(m1 - mn1);
                m0 = mn0; m1 = mn1;
                l0 *= f0; l1 *= f1;
                #pragma unroll
                for (int d = 0; d < 32; ++d) { a0[d] *= f0; a1[d] *= f1; }
            }
            #pragma unroll
            for (int i = 0; i < 4; ++i) {
                s0_[i] = __expf(s0_[i] - m0);     // bounded by e^8 when deferred
                s1_[i] = __expf(s1_[i] - m1);
            }
            l0 += (s0_[0] + s0_[1]) + (s0_[2] + s0_[3]);
            l1 += (s1_[0] + s1_[1]) + (s1_[2] + s1_[3]);
        }

        // ---- PV: each V float4 read feeds 8 FMAs
        #pragma unroll
        for (int i = 0; i < 4; ++i) {
            const float* vr = Vc + (sub + 4*i)*32;
            const float p0 = s0_[i], p1 = s1_[i];
            #pragma unroll
            for (int d4 = 0; d4 < 8; ++d4) {
                float4 vv = *(const float4*)&vr[(d4 ^ sub) << 2];
                a0[d4*4+0] += p0*vv.x; a0[d4*4+1] += p0*vv.y;
                a0[d4*4+2] += p0*vv.z; a0[d4*4+3] += p0*vv.w;
                a1[d4*4+0] += p1*vv.x; a1[d4*4+1] += p1*vv.y;
                a1[d4*4+2] += p1*vv.z; a1[d4*4+3] += p1*vv.w;
            }
        }
        __builtin_amdgcn_s_setprio(0);
    }

#undef ISSUE_TILE

    // ---- reduce across the 4-lane group; normalize only if single-pass
    l0 += __shfl_xor(l0, 1); l0 += __shfl_xor(l0, 2);
    l1 += __shfl_xor(l1, 1); l1 += __shfl_xor(l1, 2);
    const float inv0 = (NSPLIT == 1) ? 1.f / l0 : 1.f;
    const float inv1 = (NSPLIT == 1) ? 1.f / l1 : 1.f;
    #pragma unroll
    for (int d = 0; d < 32; ++d) {
        float x0 = a0[d]; x0 += __shfl_xor(x0, 1); x0 += __shfl_xor(x0, 2); a0[d] = x0 * inv0;
        float x1 = a1[d]; x1 += __shfl_xor(x1, 1); x1 += __shfl_xor(x1, 2); a1[d] = x1 * inv1;
    }

    float* obase = (NSPLIT == 1) ? outp : (outp + (size_t)split * NELEM);
    // static-index writes: 4-way branch on sub keeps arrays out of scratch
    #define WRITE_SLICE(ro, a_, off) { \
        float4 o1 = make_float4(a_[(off)+0],a_[(off)+1],a_[(off)+2],a_[(off)+3]); \
        float4 o2 = make_float4(a_[(off)+4],a_[(off)+5],a_[(off)+6],a_[(off)+7]); \
        *(float4*)&obase[(rowbase + (ro))*C_ + coloff + (off)]     = o1; \
        *(float4*)&obase[(rowbase + (ro))*C_ + coloff + (off) + 4] = o2; }
    if      (sub == 0) { WRITE_SLICE(r0, a0, 0)  WRITE_SLICE(r1, a1, 0)  }
    else if (sub == 1) { WRITE_SLICE(r0, a0, 8)  WRITE_SLICE(r1, a1, 8)  }
    else if (sub == 2) { WRITE_SLICE(r0, a0, 16) WRITE_SLICE(r1, a1, 16) }
    else               { WRITE_SLICE(r0, a0, 24) WRITE_SLICE(r1, a1, 24) }
    #undef WRITE_SLICE

    if (NSPLIT > 1 && sub == 0) {
        const size_t mlb = (size_t)split*MLROWS + ((size_t)b*NH + hh)*S_;
        pm[mlb + r0] = m0; pl[mlb + r0] = l0;
        pm[mlb + r1] = m1; pl[mlb + r1] = l1;
    }
}

// ---------------- combine the NSPLIT KV-split partials ---------------------------
template<int NSPLIT>
__global__ __launch_bounds__(256) void combine_kernel(
        const float* __restrict__ pacc, const float* __restrict__ pm,
        const float* __restrict__ pl, float* __restrict__ ctx)
{
    const int gid = blockIdx.x * 256 + threadIdx.x;   // 0 .. B_*S_*NH*8-1
    int rem = gid >> 3;
    const int h = rem & 7; rem >>= 3;
    const int s = rem % S_;
    const int b = rem / S_;

    const size_t i0 = ((size_t)b*NH + h)*S_ + s;
    float mm[NSPLIT], ll[NSPLIT], w[NSPLIT];
    float M = -1e30f;
    #pragma unroll
    for (int i = 0; i < NSPLIT; ++i) {
        mm[i] = pm[i0 + (size_t)i*MLROWS];
        ll[i] = pl[i0 + (size_t)i*MLROWS];
        M = fmaxf(M, mm[i]);
    }
    float L = 0.f;
    #pragma unroll
    for (int i = 0; i < NSPLIT; ++i) { w[i] = __expf(mm[i] - M); L += ll[i]*w[i]; }
    const float invL = 1.f / L;

    const size_t a = (size_t)gid * 4;
    float4 o = make_float4(0.f, 0.f, 0.f, 0.f);
    #pragma unroll
    for (int i = 0; i < NSPLIT; ++i) {
        const float4 x = *(const float4*)&pacc[a + (size_t)i*NELEM];
        o.x += x.x*w[i]; o.y += x.y*w[i]; o.z += x.z*w[i]; o.w += x.w*w[i];
    }
    o.x *= invL; o.y *= invL; o.z *= invL; o.w *= invL;
    *(float4*)&ctx[a] = o;
}

// ---------------- launch ---------------------------------------------------------
extern "C" void kernel_launch(void* const* d_in, const int* in_sizes, int n_in,
                              void* d_out, int out_size, void* d_ws, size_t ws_size,
                              hipStream_t stream)
{
    const float* x  = (const float*)d_in[0];
    const float* Wq = (const float*)d_in[1];
    const float* Wk = (const float*)d_in[2];
    const float* Wv = (const float*)d_in[3];
    const float* qb = (const float*)d_in[4];
    const float* vb = (const float*)d_in[5];
    const float* Wo = (const float*)d_in[6];
    const float* bo = (const float*)d_in[7];
    float* out = (float*)d_out;

    float* ws   = (float*)d_ws;
    float* q    = ws;
    float* k    = q + NELEM;
    float* v    = k + NELEM;
    float* ctx  = v + NELEM;
    float* tblf = ctx + NELEM;                         // rope table: TABN float2
    float* pacc = tblf + 2*TABN;                       // NSPLIT x NELEM

    const size_t need2 = ((size_t)(4+2)*NELEM + (size_t)2*TABN
                          + (size_t)2*2*MLROWS) * sizeof(float);

    // q,k,v projections (+bias, q pre-scaled), 64x64 tiles
    qkv_kernel<<<dim3(96, 4, 3), 256, 0, stream>>>(x, Wq, Wk, Wv, qb, vb, q, k, v);

    if (ws_size >= need2) {
        float2* tbl = (float2*)tblf;
        float* pm = pacc + (size_t)2*NELEM;
        float* pl = pm + (size_t)2*MLROWS;
        // rope via precomputed table (bit-identical double sincos, 32x fewer)
        rope_tab_kernel<<<TABN/256, 256, 0, stream>>>(tbl);
        rope_kernel<true><<<6144, 256, 0, stream>>>(q, k, tbl);
        // 3072 single-wave blocks -> 12 resident/CU -> 3 waves/SIMD
        attn_kernel<2><<<dim3(S_/32, NH, B_*2), 64, 0, stream>>>(q, k, v, pacc, pm, pl);
        combine_kernel<2><<<(B_*S_*NH*8)/256, 256, 0, stream>>>(pacc, pm, pl, ctx);
    } else {
        rope_kernel<false><<<6144, 256, 0, stream>>>(q, k, nullptr);
        attn_kernel<1><<<dim3(S_/32, NH, B_), 64, 0, stream>>>(q, k, v, ctx, nullptr, nullptr);
    }

    // output projection
    out_gemm_kernel<<<dim3(96, 4, 1), 256, 0, stream>>>(ctx, Wo, bo, out);
}